// Round 8
// baseline (84.033 us; speedup 1.0000x reference)
//
#include <hip/hip_runtime.h>

// Fused upfirdn2d: up2(FIR12,H) -> up2(FIR12,W) -> +bias -> lrelu*sqrt2
//                  -> down2(FIR12,H) -> down2(FIR12,W)
// x: (32,128,64,64) f32.
// R8: quarter-slice blocks (16 out rows), NT=256 (4 waves):
//   LDS = z[42][84] + yw[42][68] = 25.5KB -> 6 blocks/CU = 24 waves, and
//   6 independent blocks hide barrier tails (R7's 10-wave blocks packed only 2/CU).
//   Phase 2 processes ROW PAIRS (r, r+21) as float2 -> v_pk_fma_f32 eligible;
//   pair stride 21*84 fl = 7056B = 16B mod 128 -> bank tiling stays perfect.
//
// Index math:
//   z[i][c]  = sum_{j == i (mod 2)} (2*fu[j]) * x[(i-j)/2][c]
//   y[i][w]  = sum_{j == w (mod 2)} (2*fu[j]) * z[i][(w-j)/2]; lrelu(y+b)*g
//   yw[i][p] = sum_{j} fd[j] * y[i][2p+11-j]          (down-W first; commutes)
//   out[o][p]= sum_{j} fd[j] * yw[2o+11-j][p]         (down-H second)

#define NT 256
#define GAIN 1.41421356237309504880f
#define C1 (0.6f * GAIN)
#define C2 (0.4f * GAIN)

#define ZROWS 42              // quarter: out rows [o0,o0+16) -> z/yw rows [2o0, 2o0+42)
#define ZSTRIDE 84            // 336B = 80B mod 128 -> full bank rotation, row-walk
#define ZPAD 8                // local col p <-> real z col p-8 ; pads zeroed
#define YWSTRIDE 68           // 272B = 16B mod 128 -> full bank rotation, row-walk
#define RPAIR 21              // phase-2 row pair = (r, r+21)

#define ZB_OFF 0
#define YW_OFF (ZROWS * ZSTRIDE)               // 3528
#define LDS_FLOATS (YW_OFF + ZROWS * YWSTRIDE) // 6384 floats = 25536 B -> 6 blk/CU

// wave-uniform float -> SGPR
__device__ __forceinline__ float sload(float v) {
    return __uint_as_float(__builtin_amdgcn_readfirstlane(__float_as_uint(v)));
}

__global__ __launch_bounds__(NT, 6) void fused_upfirdn_lrelu(
    const float* __restrict__ x,
    const float* __restrict__ bias,
    const float* __restrict__ upf,
    const float* __restrict__ dnf,
    float* __restrict__ out)
{
    extern __shared__ float lds[];
    float* zb = lds + ZB_OFF;
    float* yw = lds + YW_OFF;

    const int t = threadIdx.x;
    const int bid = blockIdx.x;
    const int s = bid >> 2;           // slice = n*128 + c
    const int o0 = (bid & 3) << 4;    // 0,16,32,48
    const int c = s & 127;

    // filters + bias in SGPRs (uniform); fu pre-scaled by UP=2
    float fu[12], fd[12];
#pragma unroll
    for (int j = 0; j < 12; ++j) {
        fu[j] = sload(2.0f * upf[j]);
        fd[j] = sload(dnf[j]);
    }
    const float bv = sload(bias[c]);

    const float* xg = x + (size_t)s * 4096;
    float* outg = out + (size_t)s * 4096;

    // ---- Phase 1: up-H from GLOBAL x -> z local rows [0,42) (t<176);
    //      threads 176..255 zero the z pad columns. ----
    if (t < 176) {
        const int k = t >> 4;                 // 0..10 ; z local rows 4k..4k+3 (k=10: 2 rows)
        const int c4 = (t & 15) << 2;
        const int rbase = o0 - 5 + 2 * k;     // x rows rbase..rbase+6
        float4 xv[7];
#pragma unroll
        for (int d = 0; d < 7; ++d) {
            const int r = rbase + d;
            if (r >= 0 && r <= 63)
                xv[d] = *reinterpret_cast<const float4*>(xg + r * 64 + c4);
            else
                xv[d] = make_float4(0.f, 0.f, 0.f, 0.f);
        }
        float a0[4] = {0,0,0,0}, a1[4] = {0,0,0,0}, b0[4] = {0,0,0,0}, b1[4] = {0,0,0,0};
#pragma unroll
        for (int d = 0; d < 6; ++d) {         // rows 4k,4k+1 use xv[0..5], tt = 5-d
            const float w0 = fu[2 * (5 - d)], w1 = fu[2 * (5 - d) + 1];
            a0[0] += w0 * xv[d].x; a0[1] += w0 * xv[d].y; a0[2] += w0 * xv[d].z; a0[3] += w0 * xv[d].w;
            a1[0] += w1 * xv[d].x; a1[1] += w1 * xv[d].y; a1[2] += w1 * xv[d].z; a1[3] += w1 * xv[d].w;
        }
#pragma unroll
        for (int d = 1; d < 7; ++d) {         // rows 4k+2,4k+3 use xv[1..6], tt = 6-d
            const float w0 = fu[2 * (6 - d)], w1 = fu[2 * (6 - d) + 1];
            b0[0] += w0 * xv[d].x; b0[1] += w0 * xv[d].y; b0[2] += w0 * xv[d].z; b0[3] += w0 * xv[d].w;
            b1[0] += w1 * xv[d].x; b1[1] += w1 * xv[d].y; b1[2] += w1 * xv[d].z; b1[3] += w1 * xv[d].w;
        }
        float* zr = zb + (4 * k) * ZSTRIDE + ZPAD + c4;
        *reinterpret_cast<float4*>(zr)               = make_float4(a0[0], a0[1], a0[2], a0[3]);
        *reinterpret_cast<float4*>(zr + ZSTRIDE)     = make_float4(a1[0], a1[1], a1[2], a1[3]);
        if (k < 10) {
            *reinterpret_cast<float4*>(zr + 2 * ZSTRIDE) = make_float4(b0[0], b0[1], b0[2], b0[3]);
            *reinterpret_cast<float4*>(zr + 3 * ZSTRIDE) = make_float4(b1[0], b1[1], b1[2], b1[3]);
        }
    } else {
        // zero z pad cols [0,8) and [72,84): 5 float4 per row x 42 rows = 210 tasks
        for (int pt = t - 176; pt < 210; pt += 80) {
            const int rl = pt / 5;
            const int p = pt - rl * 5;
            const int col = (p < 2) ? (p << 2) : (72 + ((p - 2) << 2));
            *reinterpret_cast<float4*>(zb + rl * ZSTRIDE + col) = make_float4(0.f, 0.f, 0.f, 0.f);
        }
    }
    __syncthreads();

    // ---- Phase 2 (merged upW+lrelu+downW), ROW-PAIR float2 version:
    //      task = (cg, r): rows r (lo) and r+21 (hi) as float2 lanes.
    //      6+6 b128 z-reads -> packed y pairs -> acc[8] float2 -> 2+2 b128 writes. ----
    {
        const int cg = t / 24;                // 0..10 ; r fast-varying, padded to 24
        const int r  = t - cg * 24;
        if (cg < 8 && r < RPAIR) {
            const float* zrA = zb + r * ZSTRIDE + (cg << 3);          // row r
            const float* zrB = zrA + RPAIR * ZSTRIDE;                 // row r+21
            float2 zv[24];
#pragma unroll
            for (int q = 0; q < 6; ++q) {
                const float4 va = *reinterpret_cast<const float4*>(zrA + (q << 2));
                const float4 vb = *reinterpret_cast<const float4*>(zrB + (q << 2));
                zv[4 * q + 0] = make_float2(va.x, vb.x);
                zv[4 * q + 1] = make_float2(va.y, vb.y);
                zv[4 * q + 2] = make_float2(va.z, vb.z);
                zv[4 * q + 3] = make_float2(va.w, vb.w);
            }
            float2 acc[8];
#pragma unroll
            for (int e = 0; e < 8; ++e) acc[e] = make_float2(0.f, 0.f);
#pragma unroll
            for (int v = 0; v < 13; ++v) {    // y[2v], y[2v+1] for both rows
                float2 a0 = make_float2(bv, bv), a1 = make_float2(bv, bv);
#pragma unroll
                for (int tt = 0; tt < 6; ++tt) {
                    const float2 zz = zv[v + 8 - tt];
                    const float w0 = fu[2 * tt], w1 = fu[2 * tt + 1];
                    a0.x += w0 * zz.x; a0.y += w0 * zz.y;
                    a1.x += w1 * zz.x; a1.y += w1 * zz.y;
                }
                float2 y0, y1;                 // g*lrelu(.) elementwise
                y0.x = C1 * a0.x + C2 * fabsf(a0.x); y0.y = C1 * a0.y + C2 * fabsf(a0.y);
                y1.x = C1 * a1.x + C2 * fabsf(a1.x); y1.y = C1 * a1.y + C2 * fabsf(a1.y);
#pragma unroll
                for (int e = 0; e < 8; ++e) { // tap j = 2e+11-u (compile-time per (v,e))
                    const int j0 = 2 * e + 11 - 2 * v;       // u = 2v
                    const int j1 = 2 * e + 10 - 2 * v;       // u = 2v+1
                    if (j0 >= 0 && j0 <= 11) { acc[e].x += fd[j0] * y0.x; acc[e].y += fd[j0] * y0.y; }
                    if (j1 >= 0 && j1 <= 11) { acc[e].x += fd[j1] * y1.x; acc[e].y += fd[j1] * y1.y; }
                }
            }
            float* wrA = yw + r * YWSTRIDE + (cg << 3);
            float* wrB = wrA + RPAIR * YWSTRIDE;
            *reinterpret_cast<float4*>(wrA)     = make_float4(acc[0].x, acc[1].x, acc[2].x, acc[3].x);
            *reinterpret_cast<float4*>(wrA + 4) = make_float4(acc[4].x, acc[5].x, acc[6].x, acc[7].x);
            *reinterpret_cast<float4*>(wrB)     = make_float4(acc[0].y, acc[1].y, acc[2].y, acc[3].y);
            *reinterpret_cast<float4*>(wrB + 4) = make_float4(acc[4].y, acc[5].y, acc[6].y, acc[7].y);
        }
    }
    __syncthreads();

    // ---- Phase 3: down-H on yw -> GLOBAL out.  t<64: 4 out rows x 4 cols
    //      from 18 yw rows (contiguous 16B lane stride: bank-clean). ----
    if (t < 64) {
        const int eg = t >> 4;                // 0..3 ; out rows o0+4eg .. o0+4eg+3
        const int col4 = (t & 15) << 2;       // 0..60
        const float* wr = yw + (eg << 3) * YWSTRIDE + col4;    // yw rows 8eg..8eg+17
        float acc[4][4] = {{0,0,0,0},{0,0,0,0},{0,0,0,0},{0,0,0,0}};
#pragma unroll
        for (int r = 0; r < 18; ++r) {
            const float4 v = *reinterpret_cast<const float4*>(wr + r * YWSTRIDE);
#pragma unroll
            for (int e = 0; e < 4; ++e) {
                if (r >= 2 * e && r <= 2 * e + 11) {           // compile-time per (r,e)
                    const float ww = fd[11 - r + 2 * e];
                    acc[e][0] += ww * v.x; acc[e][1] += ww * v.y;
                    acc[e][2] += ww * v.z; acc[e][3] += ww * v.w;
                }
            }
        }
#pragma unroll
        for (int e = 0; e < 4; ++e)
            *reinterpret_cast<float4*>(outg + (o0 + (eg << 2) + e) * 64 + col4) =
                make_float4(acc[e][0], acc[e][1], acc[e][2], acc[e][3]);
    }
}

extern "C" void kernel_launch(void* const* d_in, const int* in_sizes, int n_in,
                              void* d_out, int out_size, void* d_ws, size_t ws_size,
                              hipStream_t stream) {
    const float* x    = (const float*)d_in[0];
    const float* bias = (const float*)d_in[1];
    const float* upf  = (const float*)d_in[2];
    const float* dnf  = (const float*)d_in[3];
    float* out = (float*)d_out;

    const int n_blocks = 32 * 128 * 4;   // four quarter-slices per (n,c)
    const size_t lds_bytes = (size_t)LDS_FLOATS * sizeof(float);
    hipLaunchKernelGGL(fused_upfirdn_lrelu, dim3(n_blocks), dim3(NT),
                       lds_bytes, stream, x, bias, upf, dnf, out);
}

// Round 9
// 73.239 us; speedup vs baseline: 1.1474x; 1.1474x over previous
//
#include <hip/hip_runtime.h>

// Fused upfirdn2d: up2(FIR12,H) -> up2(FIR12,W) -> +bias -> lrelu*sqrt2
//                  -> down2(FIR12,H) -> down2(FIR12,W)
// x: (32,128,64,64) f32.
// R9: R5's separate-phase structure (lowest VALU issue of all rounds) at
//     QUARTER-slice granularity with NT=512:
//     - 8-wave blocks pack exactly 2 waves/SIMD -> 4 blocks/CU = 32/32 waves
//       (R5's 16-wave blocks gave 2 lockstep blocks; R7/R8 packed worse).
//     - LDS = z[42][84] + y[42][148] = 39.0KB (yw aliases z) <= 40KB for 4 blk.
//     - abs-trick lrelu: g*lrelu(a) = 0.6g*a + 0.4g*|a| (|.| is a VOP3 modifier).
//     - P1 interior tasks (M in [5,63]) do unchecked global loads.
//     fp32 packed math (v_pk_fma_f32) is NOT faster on gfx950 (157.3TF = scalar
//     rate) - R8's float2 attempt confirmed; stay scalar.
//
// Index math:
//   z[i][c]  = sum_{j == i (mod 2)} (2*fu[j]) * x[(i-j)/2][c]
//   y[i][w]  = sum_{j == w (mod 2)} (2*fu[j]) * z[i][(w-j)/2]; lrelu(y+b)*g
//   yw[i][p] = sum_{j} fd[j] * y[i][2p+11-j]          (down-W; commutes w/ down-H)
//   out[o][p]= sum_{j} fd[j] * yw[2o+11-j][p]         (down-H)

#define NT 512
#define GAIN 1.41421356237309504880f
#define C1 (0.6f * GAIN)
#define C2 (0.4f * GAIN)

#define ZROWS 42              // quarter: out rows [o0,o0+16) -> z/y rows [2o0,2o0+42)
#define ZSTRIDE 84            // 336B = 80B mod 128 -> full 8-slot rotation, row-walk
#define ZPAD 8                // local col p <-> real z col p-8 ; pads zeroed
#define YSTRIDE 148           // 592B = 80B mod 128 -> full rotation, row-walk
#define YWSTRIDE 68           // 272B = 16B mod 128 -> full rotation, row-walk

#define ZB_OFF 0
#define YB_OFF (ZROWS * ZSTRIDE)              // 3528
#define YW_OFF 0                              // yw[42][68]=2856 aliases zb (dead after P2)
#define LDS_FLOATS (YB_OFF + ZROWS * YSTRIDE) // 9744 floats = 38976 B -> 4 blk/CU

// wave-uniform float -> SGPR
__device__ __forceinline__ float sload(float v) {
    return __uint_as_float(__builtin_amdgcn_readfirstlane(__float_as_uint(v)));
}

__global__ __launch_bounds__(NT, 8) void fused_upfirdn_lrelu(
    const float* __restrict__ x,
    const float* __restrict__ bias,
    const float* __restrict__ upf,
    const float* __restrict__ dnf,
    float* __restrict__ out)
{
    extern __shared__ float lds[];
    float* zb = lds + ZB_OFF;
    float* yb = lds + YB_OFF;
    float* yw = lds + YW_OFF;

    const int t = threadIdx.x;
    const int bid = blockIdx.x;
    const int s = bid >> 2;           // slice = n*128 + c
    const int o0 = (bid & 3) << 4;    // 0,16,32,48
    const int c = s & 127;

    // filters + bias in SGPRs (uniform); fu pre-scaled by UP=2
    float fu[12], fd[12];
#pragma unroll
    for (int j = 0; j < 12; ++j) {
        fu[j] = sload(2.0f * upf[j]);
        fd[j] = sload(dnf[j]);
    }
    const float bv = sload(bias[c]);

    const float* xg = x + (size_t)s * 4096;
    float* outg = out + (size_t)s * 4096;

    // ---- P1: up-H from GLOBAL x -> z local rows [0,42).  t<336: task=(m,c4),
    //      z rows 2m,2m+1 from x rows M-5..M (M=o0+m), interior unchecked.
    //      t>=336: zero z pad cols [0,8) and [72,84). ----
    if (t < 336) {
        const int m = t >> 4;                 // 0..20
        const int c4 = (t & 15) << 2;
        const int M = o0 + m;
        float4 xv[6];
        if (M >= 5 && M <= 63) {              // interior: no bounds checks
#pragma unroll
            for (int d = 0; d < 6; ++d)
                xv[d] = *reinterpret_cast<const float4*>(xg + (M - 5 + d) * 64 + c4);
        } else {
#pragma unroll
            for (int d = 0; d < 6; ++d) {
                const int r = M - 5 + d;
                xv[d] = (r >= 0 && r <= 63)
                      ? *reinterpret_cast<const float4*>(xg + r * 64 + c4)
                      : make_float4(0.f, 0.f, 0.f, 0.f);
            }
        }
        float a0[4] = {0,0,0,0}, a1[4] = {0,0,0,0};
#pragma unroll
        for (int d = 0; d < 6; ++d) {         // tt = 5-d
            const float w0 = fu[2 * (5 - d)], w1 = fu[2 * (5 - d) + 1];
            a0[0] += w0 * xv[d].x; a0[1] += w0 * xv[d].y; a0[2] += w0 * xv[d].z; a0[3] += w0 * xv[d].w;
            a1[0] += w1 * xv[d].x; a1[1] += w1 * xv[d].y; a1[2] += w1 * xv[d].z; a1[3] += w1 * xv[d].w;
        }
        float* zr = zb + (2 * m) * ZSTRIDE + ZPAD + c4;
        *reinterpret_cast<float4*>(zr)           = make_float4(a0[0], a0[1], a0[2], a0[3]);
        *reinterpret_cast<float4*>(zr + ZSTRIDE) = make_float4(a1[0], a1[1], a1[2], a1[3]);
    } else {
        // 5 float4 pad-writes per row x 42 rows = 210 tasks over 176 threads
        for (int pt = t - 336; pt < 210; pt += 176) {
            const int rl = pt / 5;
            const int p = pt - rl * 5;
            const int col = (p < 2) ? (p << 2) : (72 + ((p - 2) << 2));
            *reinterpret_cast<float4*>(zb + rl * ZSTRIDE + col) = make_float4(0.f, 0.f, 0.f, 0.f);
        }
    }
    __syncthreads();

    // ---- P2: up-W + bias + lrelu -> y[42][148].  t<378: task=(cg, il),
    //      il fast-varying (row-walk, bank-rotated); 16 y per task. ----
    if (t < 378) {
        const int cg = t / 42;                // 0..8
        const int il = t - cg * 42;
        const int mbase = cg << 3;
        const float* zr = zb + il * ZSTRIDE + mbase;   // local col = real col + 8
        float zv[16];
#pragma unroll
        for (int q = 0; q < 4; ++q) {
            const float4 v = *reinterpret_cast<const float4*>(zr + (q << 2));
            zv[4 * q] = v.x; zv[4 * q + 1] = v.y; zv[4 * q + 2] = v.z; zv[4 * q + 3] = v.w;
        }
        float yv[16];
#pragma unroll
        for (int e = 0; e < 8; ++e) {         // m = mbase+e -> w = 2m, 2m+1
            float a0 = bv, a1 = bv;
#pragma unroll
            for (int tt = 0; tt < 6; ++tt) {
                const float zz = zv[8 + e - tt];
                a0 += fu[2 * tt]     * zz;
                a1 += fu[2 * tt + 1] * zz;
            }
            yv[2 * e]     = C1 * a0 + C2 * fabsf(a0);   // g*lrelu
            yv[2 * e + 1] = C1 * a1 + C2 * fabsf(a1);
        }
        float* yr = yb + il * YSTRIDE + (mbase << 1);
#pragma unroll
        for (int q = 0; q < 4; ++q)
            *reinterpret_cast<float4*>(yr + (q << 2)) =
                make_float4(yv[4 * q], yv[4 * q + 1], yv[4 * q + 2], yv[4 * q + 3]);
    }
    __syncthreads();

    // ---- P3: down-W on y -> yw[42][64] (aliases zb).  t<336: task=(cg, il),
    //      8 outputs from 28 y; il fast-varying. ----
    if (t < 336) {
        const int cg = t / 42;                // 0..7 ; outputs p = 8cg..8cg+7
        const int il = t - cg * 42;
        const float* yr = yb + il * YSTRIDE + (cg << 4);   // y cols 16cg..16cg+27
        float w[28];
#pragma unroll
        for (int q = 0; q < 7; ++q) {
            const float4 v = *reinterpret_cast<const float4*>(yr + (q << 2));
            w[4 * q] = v.x; w[4 * q + 1] = v.y; w[4 * q + 2] = v.z; w[4 * q + 3] = v.w;
        }
        float rv[8];
#pragma unroll
        for (int e = 0; e < 8; ++e) {         // p = 8cg+e : y cols 2p..2p+11
            float a = 0.0f;
#pragma unroll
            for (int j = 0; j < 12; ++j) a += fd[j] * w[2 * e + 11 - j];
            rv[e] = a;
        }
        float* wr = yw + il * YWSTRIDE + (cg << 3);
        *reinterpret_cast<float4*>(wr)     = make_float4(rv[0], rv[1], rv[2], rv[3]);
        *reinterpret_cast<float4*>(wr + 4) = make_float4(rv[4], rv[5], rv[6], rv[7]);
    }
    __syncthreads();

    // ---- P4: down-H on yw -> GLOBAL out.  t<256: task=(o, col4): 1 out row
    //      x 4 cols from 12 yw rows; 8-lane groups read 128B contiguous. ----
    if (t < 256) {
        const int o = t >> 4;                 // 0..15 ; out row o0+o
        const int col4 = (t & 15) << 2;       // 0..60
        const float* wr = yw + (2 * o) * YWSTRIDE + col4;   // yw rows 2o..2o+11
        float a0 = 0.f, a1 = 0.f, a2 = 0.f, a3 = 0.f;
#pragma unroll
        for (int rr = 0; rr < 12; ++rr) {     // j = 11-rr
            const float4 v = *reinterpret_cast<const float4*>(wr + rr * YWSTRIDE);
            const float ww = fd[11 - rr];
            a0 += ww * v.x; a1 += ww * v.y; a2 += ww * v.z; a3 += ww * v.w;
        }
        *reinterpret_cast<float4*>(outg + (o0 + o) * 64 + col4) =
            make_float4(a0, a1, a2, a3);
    }
}

extern "C" void kernel_launch(void* const* d_in, const int* in_sizes, int n_in,
                              void* d_out, int out_size, void* d_ws, size_t ws_size,
                              hipStream_t stream) {
    const float* x    = (const float*)d_in[0];
    const float* bias = (const float*)d_in[1];
    const float* upf  = (const float*)d_in[2];
    const float* dnf  = (const float*)d_in[3];
    float* out = (float*)d_out;

    const int n_blocks = 32 * 128 * 4;   // four quarter-slices per (n,c)
    const size_t lds_bytes = (size_t)LDS_FLOATS * sizeof(float);
    hipLaunchKernelGGL(fused_upfirdn_lrelu, dim3(n_blocks), dim3(NT),
                       lds_bytes, stream, x, bias, upf, dnf, out);
}